// Round 5
// baseline (853.492 us; speedup 1.0000x reference)
//
#include <hip/hip_runtime.h>
#include <hip/hip_bf16.h>

#define BLOCK 256
#define GRID 2048
#define UNROLL 8

typedef float f4 __attribute__((ext_vector_type(4)));  // native vec for nontemporal builtin

// out[b,i,j,h] = W[h, rel_pos[b,i,j]] — float32 gather, 12 floats = 3 float4
// chunks per record. Persistent grid: 2048 blocks x 256 thr; LDS table loaded
// once per block; steady-state loop has NO barriers and 8 independent
// load->gather->store chains in flight per thread (MLP like the fill kernel).
// 50,331,648 chunks = 2048*256*8*12 exactly -> unguarded hot path.
__global__ __launch_bounds__(BLOCK) void gather12_v5(
    const int* __restrict__ rel_pos,
    const float* __restrict__ W,        // [12][64] float32
    f4* __restrict__ out,
    unsigned int total_chunks)
{
    __shared__ float tab[64 * 12];      // tab[c*12+h] = W[h][c]; 16B-aligned chunks
    const int t = threadIdx.x;
    for (int i = t; i < 768; i += BLOCK) {
        int h = i >> 6;                 // 0..11
        int c = i & 63;                 // 0..63
        tab[c * 12 + h] = W[i];
    }
    __syncthreads();                    // once per block, amortized over 96 chunks/thread

    const unsigned int nth = GRID * BLOCK;              // 524288 threads
    const unsigned int q0 = blockIdx.x * BLOCK + t;

    for (unsigned int base = q0; base < total_chunks; base += nth * UNROLL) {
        unsigned int cc[UNROLL], ss[UNROLL];
#pragma unroll
        for (int u = 0; u < UNROLL; ++u) {              // 8 independent idx loads
            unsigned int q = base + u * nth;
            unsigned int p = q / 3u;                    // const-divisor magic mul
            ss[u] = q - p * 3u;
            cc[u] = (q < total_chunks) ? (unsigned int)rel_pos[p] : 0u;
        }
        f4 v[UNROLL];
#pragma unroll
        for (int u = 0; u < UNROLL; ++u)                // 8 independent ds_read_b128
            v[u] = *(const f4*)(tab + cc[u] * 12u + 4u * ss[u]);
#pragma unroll
        for (int u = 0; u < UNROLL; ++u) {              // 8 independent nt dwordx4 stores
            unsigned int q = base + u * nth;
            if (q < total_chunks)
                __builtin_nontemporal_store(v[u], &out[q]);
        }
    }
}

extern "C" void kernel_launch(void* const* d_in, const int* in_sizes, int n_in,
                              void* d_out, int out_size, void* d_ws, size_t ws_size,
                              hipStream_t stream)
{
    const int* rel_pos = (const int*)d_in[0];
    // d_in[1] = hidden_states: unused (reference only uses its dtype)
    const float* W = (const float*)d_in[2];

    const unsigned int total_chunks = (unsigned int)((long long)in_sizes[0] * 3ll);

    gather12_v5<<<GRID, BLOCK, 0, stream>>>(rel_pos, W, (f4*)d_out, total_chunks);
}

// Round 6
// 832.008 us; speedup vs baseline: 1.0258x; 1.0258x over previous
//
#include <hip/hip_runtime.h>
#include <hip/hip_bf16.h>

#define BLOCK 256
#define TILES 4                          // records per block = TILES*BLOCK = 1024
#define RPB   (TILES * BLOCK)

typedef float f4 __attribute__((ext_vector_type(4)));

// out[b,i,j,h] = W[h, rel_pos[b,i,j]] — float32 gather, 12 floats = 3 f4/record.
// Block owns 1024 records = 3072 f4-chunks. Phase 1: coalesced idx load (4/thr)
// -> LDS cls[1024]; W^T -> LDS tab[64][12]. One barrier. Phase 2: 12 independent
// ds_read_b128 gathers + 12 independent PLAIN coalesced dwordx4 stores per
// thread (A/B vs nt: fill kernel reaches 6.3 TB/s with plain stores).
__global__ __launch_bounds__(BLOCK) void gather12_v6(
    const int* __restrict__ rel_pos,
    const float* __restrict__ W,         // [12][64] float32
    f4* __restrict__ out,
    unsigned int n_rec)
{
    __shared__ float tab[64 * 12];       // tab[c*12+h] = W[h][c]; 16B-aligned chunks
    __shared__ int cls[RPB];

    const int t = threadIdx.x;
    for (int i = t; i < 768; i += BLOCK) {
        int h = i >> 6;
        int c = i & 63;
        tab[c * 12 + h] = W[i];
    }

    const unsigned int recBase = blockIdx.x * RPB;
#pragma unroll
    for (int k = 0; k < TILES; ++k) {    // 4 coalesced dword loads per thread
        unsigned int r = recBase + k * BLOCK + t;
        cls[k * BLOCK + t] = (r < n_rec) ? rel_pos[r] : 0;
    }
    __syncthreads();

    const unsigned long long chunkBase = (unsigned long long)recBase * 3ull;
    const unsigned long long total_chunks = (unsigned long long)n_rec * 3ull;

    f4 v[3 * TILES];
#pragma unroll
    for (int k = 0; k < 3 * TILES; ++k) {           // 12 independent LDS gathers
        unsigned int j = (unsigned int)t + BLOCK * k;  // 0..3071 within tile group
        unsigned int p = j / 3u;                    // const-divisor magic mul
        unsigned int s = j - p * 3u;
        unsigned int c = (unsigned int)cls[p];
        v[k] = *(const f4*)(tab + c * 12u + 4u * s);
    }
#pragma unroll
    for (int k = 0; k < 3 * TILES; ++k) {           // 12 independent plain stores
        unsigned int j = (unsigned int)t + BLOCK * k;
        if (chunkBase + j < total_chunks)
            out[chunkBase + j] = v[k];
    }
}

extern "C" void kernel_launch(void* const* d_in, const int* in_sizes, int n_in,
                              void* d_out, int out_size, void* d_ws, size_t ws_size,
                              hipStream_t stream)
{
    const int* rel_pos = (const int*)d_in[0];
    // d_in[1] = hidden_states: unused (reference only uses its dtype)
    const float* W = (const float*)d_in[2];

    const unsigned int n_rec = (unsigned int)in_sizes[0];     // 16,777,216
    const int blocks = (int)((n_rec + RPB - 1) / RPB);        // 16384

    gather12_v6<<<blocks, BLOCK, 0, stream>>>(rel_pos, W, (f4*)d_out, n_rec);
}